// Round 7
// baseline (122.295 us; speedup 1.0000x reference)
//
#include <hip/hip_runtime.h>
#include <math.h>

#define NDIRS 64
#define NBIN 65
#define HSTRIDE 66               // 65 bins + 1 spill-guard slot per row
#define HIST1 (NDIRS*HSTRIDE)    // 4224 floats per wave-private hist
#define THREADS 256
#define WPB 4
#define NBLK 512                 // 512*4 waves, each owns a pair of strips
#define ROWF (NDIRS*NBIN)        // 4160

static constexpr float INV = 0.28867513459481287f; // 1/(2*sqrt(3))

__device__ __forceinline__ float rdlane(float v, int t) {
  return __int_as_float(__builtin_amdgcn_readlane(__float_as_int(v), t));
}

struct Agg { float T, v1, v2, v3, v4, v5, v6, v7; };

__device__ __forceinline__ Agg load_strip(const float* __restrict__ x,
                                          int strip, int lane) {
  const int i = strip >> 6, j = strip & 63, l = lane;
  const float* p = x + (strip << 6) + l;
  const int dL = (l < 63) ? 1 : 0;
  const int dJ = (j < 63) ? 64 : 0;
  const int dI = (i < 63) ? 4096 : 0;
  const bool iv = dI != 0, jv = dJ != 0, lv = dL != 0;
  const float x000 = p[0],       x001 = p[dL];
  const float x010 = p[dJ],      x011 = p[dJ+dL];
  const float x100 = p[dI],      x101 = p[dI+dL];
  const float x110 = p[dI+dJ],   x111 = p[dI+dJ+dL];
  const float e0m = fmaxf(x000, x100);
  const float e1m = fmaxf(x000, x010);
  const float e2m = fmaxf(x000, x001);
  const float s12 = fmaxf(fmaxf(e1m, x001), x011);
  const float s02 = fmaxf(fmaxf(e0m, x001), x101);
  const float s01 = fmaxf(fmaxf(e0m, x010), x110);
  const float cc  = fmaxf(fmaxf(s01, fmaxf(x001, x101)), fmaxf(x011, x111));
  Agg a;
  a.v1 = iv ? -e0m : 0.f;
  a.v2 = jv ? -e1m : 0.f;
  a.v3 = lv ? -e2m : 0.f;
  a.v4 = (jv && lv) ? s12 : 0.f;
  a.v5 = (iv && lv) ? s02 : 0.f;
  a.v6 = (iv && jv) ? s01 : 0.f;
  a.v7 = (iv && jv && lv) ? -cc : 0.f;
  a.T  = x000 + a.v1+a.v2+a.v3+a.v4+a.v5+a.v6+a.v7;
  return a;
}

__global__ __launch_bounds__(THREADS) void wect_hist(
    const float* __restrict__ x, const float* __restrict__ dirs,
    float* __restrict__ accum) {
  __shared__ float hist[WPB * HIST1];     // 67,584 B -> 2 blocks/CU
  const int tid = threadIdx.x;
  const int lane = tid & 63;
  const int wid  = tid >> 6;

  float4* h4 = (float4*)hist;
  for (int idx = tid; idx < WPB * HIST1 / 4; idx += THREADS)
    h4[idx] = make_float4(0.f, 0.f, 0.f, 0.f);
  __syncthreads();

  // lane = DIRECTION constants (pre-scaled by 1/dh)
  const float D0 = dirs[3*lane+0] * INV;
  const float D1 = dirs[3*lane+1] * INV;
  const float D2 = dirs[3*lane+2] * INV;
  const float Q1 = fmaxf(D0, 0.f);
  const float Q2 = fmaxf(D1, 0.f);
  const float Q3 = fmaxf(D2, 0.f);
  const float Q4 = Q2 + Q3;
  const float Q5 = Q1 + Q3;
  const float Q6 = Q1 + Q2;
  const float Q7 = Q1 + Q2 + Q3;

  float* __restrict__ myrow = hist + wid * HIST1 + lane * HSTRIDE;

  // one PAIR of strips per wave: (2m, 2m+1) -> same i, j even / j+1.
  // |uB - uA| = |D1| < 0.29  =>  ibB - ibA in {-1,0,1} (merge cases below).
  const int pm = blockIdx.x * WPB + wid;        // [0, 2048)
  const int sA = 2 * pm;
  const Agg A = load_strip(x, sA,     lane);    // lane = cell for load phase
  const Agg B = load_strip(x, sA + 1, lane);

  const int i = sA >> 6, jA = sA & 63;
  const float u0A = (float)i * D0 + (float)jA * D1;   // per-lane(dir)

  #pragma unroll 8
  for (int t = 0; t < 64; ++t) {
    // broadcast cell t's aggregates for both strips (VALU, no LDS latency)
    const float TA = rdlane(A.T, t),  TB = rdlane(B.T, t);
    const float a1 = rdlane(A.v1, t), b1 = rdlane(B.v1, t);
    const float a2 = rdlane(A.v2, t), b2 = rdlane(B.v2, t);
    const float a3 = rdlane(A.v3, t), b3 = rdlane(B.v3, t);
    const float a4 = rdlane(A.v4, t), b4 = rdlane(B.v4, t);
    const float a5 = rdlane(A.v5, t), b5 = rdlane(B.v5, t);
    const float a6 = rdlane(A.v6, t), b6 = rdlane(B.v6, t);
    const float a7 = rdlane(A.v7, t), b7 = rdlane(B.v7, t);

    const float uA  = fmaf((float)t, D2, u0A);
    const float bfA = ceilf(uA);
    const float frA = bfA - uA;
    const int   ibA = (int)bfA + 32;            // in [1,64]
    const float uB  = uA + D1;
    const float bfB = ceilf(uB);
    const float frB = bfB - uB;
    const int   ibB = (int)bfB + 32;            // in [1,64]

    float SA = 0.f;
    SA += (Q1 > frA) ? a1 : 0.f;
    SA += (Q2 > frA) ? a2 : 0.f;
    SA += (Q3 > frA) ? a3 : 0.f;
    SA += (Q4 > frA) ? a4 : 0.f;
    SA += (Q5 > frA) ? a5 : 0.f;
    SA += (Q6 > frA) ? a6 : 0.f;
    SA += (Q7 > frA) ? a7 : 0.f;
    float SB = 0.f;
    SB += (Q1 > frB) ? b1 : 0.f;
    SB += (Q2 > frB) ? b2 : 0.f;
    SB += (Q3 > frB) ? b3 : 0.f;
    SB += (Q4 > frB) ? b4 : 0.f;
    SB += (Q5 > frB) ? b5 : 0.f;
    SB += (Q6 > frB) ? b6 : 0.f;
    SB += (Q7 > frB) ? b7 : 0.f;

    const float dA0 = TA - SA, dA1 = SA;
    float dB0 = TB - SB, dB1 = SB;
    // collision merge: reads (below) all precede writes; writes go A then B,
    // so B's writes must absorb A's delta wherever addresses collide.
    const int dlt = ibB - ibA;                  // in {-1,0,1}
    dB0 += (dlt == 0) ? dA0 : ((dlt == 1)  ? dA1 : 0.f);
    dB1 += (dlt == 0) ? dA1 : ((dlt == -1) ? dA0 : 0.f);

    float* aP = myrow + ibA;
    float* bP = myrow + ibB;
    const float rA0 = aP[0], rA1 = aP[1];       // all 4 reads BEFORE any write
    const float rB0 = bP[0], rB1 = bP[1];       // (source order is binding)
    aP[0] = rA0 + dA0;
    aP[1] = rA1 + dA1;                          // ib==64 -> guard slot, S==0
    bP[0] = rB0 + dB0;
    bP[1] = rB1 + dB1;
  }

  __syncthreads();
  // sum the 4 wave-private copies; private partial row per block (no atomics)
  float* __restrict__ obase = accum + blockIdx.x * ROWF;
  for (int z = tid; z < ROWF; z += THREADS) {
    const int r = z / NBIN, c = z - r * NBIN;
    const int li = r * HSTRIDE + c;
    obase[z] = hist[li] + hist[HIST1 + li]
             + hist[2*HIST1 + li] + hist[3*HIST1 + li];
  }
}

__global__ __launch_bounds__(512) void wect_scan(
    const float* __restrict__ accum, float* __restrict__ out) {
  __shared__ float red[8 * NBIN];
  __shared__ float s[NBIN];
  const int k = blockIdx.x, tid = threadIdx.x;
  for (int z = tid; z < 8 * NBIN; z += 512) {   // 520 items > 512 thr: stride
    const int g = z / NBIN, c = z - g * NBIN;
    float v = 0.f;
    for (int r = g; r < NBLK; r += 8) v += accum[r * ROWF + k * NBIN + c];
    red[z] = v;
  }
  __syncthreads();
  if (tid < NBIN) {
    float v = 0.f;
    #pragma unroll
    for (int gg = 0; gg < 8; ++gg) v += red[gg * NBIN + tid];
    s[tid] = v;
  }
  __syncthreads();
  for (int off = 1; off < NBIN; off <<= 1) {
    float a = 0.f;
    if (tid < NBIN && tid >= off) a = s[tid - off];
    __syncthreads();
    if (tid < NBIN && tid >= off) s[tid] += a;
    __syncthreads();
  }
  if (tid < NBIN) out[k * NBIN + tid] = s[tid];
}

extern "C" void kernel_launch(void* const* d_in, const int* in_sizes, int n_in,
                              void* d_out, int out_size, void* d_ws, size_t ws_size,
                              hipStream_t stream) {
  const float* x = (const float*)d_in[0];
  const float* dirs = (const float*)d_in[1];
  float* out = (float*)d_out;
  float* accum = (float*)d_ws;   // NBLK*ROWF floats = 8.5 MB, fully overwritten

  wect_hist<<<NBLK, THREADS, 0, stream>>>(x, dirs, accum);
  wect_scan<<<NDIRS, 512, 0, stream>>>(accum, out);
}